// Round 1
// baseline (501.310 us; speedup 1.0000x reference)
//
#include <hip/hip_runtime.h>

typedef float  f32x4 __attribute__((ext_vector_type(4)));
typedef short  s16x8 __attribute__((ext_vector_type(8)));
typedef unsigned short u16x4 __attribute__((ext_vector_type(4)));

#define AS1 __attribute__((address_space(1)))
#define AS3 __attribute__((address_space(3)))

__device__ __forceinline__ unsigned short f2bf(float x){
    union { float f; unsigned int u; } v; v.f = x;
    unsigned int r = v.u + 0x7FFFu + ((v.u >> 16) & 1u);   // RNE
    return (unsigned short)(r >> 16);
}

__device__ __forceinline__ void gload16(const unsigned short* g, unsigned short* l){
    __builtin_amdgcn_global_load_lds((const AS1 void*)g, (AS3 void*)l, 16, 0, 0);
}

__device__ __forceinline__ void mfma16(f32x4& c, s16x8 a, s16x8 b){
    asm volatile("v_mfma_f32_16x16x32_bf16 %0, %1, %2, %0" : "+v"(c) : "v"(a), "v"(b));
}

// ---------------------------------------------------------------------------
// Row l2-normalize [rows][1024] f32 -> bf16. One 256-thread block per row.
// ---------------------------------------------------------------------------
__global__ __launch_bounds__(256) void norm_rows_bf16(const float* __restrict__ in,
                                                      unsigned short* __restrict__ out){
    const int row = blockIdx.x;
    const int t   = threadIdx.x;
    f32x4 x = ((const f32x4*)(in + (size_t)row * 1024))[t];
    float ss = x[0]*x[0] + x[1]*x[1] + x[2]*x[2] + x[3]*x[3];
    #pragma unroll
    for (int o = 32; o > 0; o >>= 1) ss += __shfl_xor(ss, o);
    __shared__ float red[4];
    if ((t & 63) == 0) red[t >> 6] = ss;
    __syncthreads();
    float tot = red[0] + red[1] + red[2] + red[3];
    float inv = 1.0f / fmaxf(sqrtf(tot), 1e-12f);
    u16x4 o;
    #pragma unroll
    for (int j = 0; j < 4; ++j) o[j] = f2bf(x[j] * inv);
    ((u16x4*)(out + (size_t)row * 1024))[t] = o;
}

// ---------------------------------------------------------------------------
// Final in-place row l2-normalize of d_out [N][1024] f32.
// ---------------------------------------------------------------------------
__global__ __launch_bounds__(256) void norm_rows_f32(float* __restrict__ buf){
    const int row = blockIdx.x;
    const int t   = threadIdx.x;
    f32x4* p = (f32x4*)(buf + (size_t)row * 1024);
    f32x4 x = p[t];
    float ss = x[0]*x[0] + x[1]*x[1] + x[2]*x[2] + x[3]*x[3];
    #pragma unroll
    for (int o = 32; o > 0; o >>= 1) ss += __shfl_xor(ss, o);
    __shared__ float red[4];
    if ((t & 63) == 0) red[t >> 6] = ss;
    __syncthreads();
    float tot = red[0] + red[1] + red[2] + red[3];
    float inv = 1.0f / fmaxf(sqrtf(tot), 1e-12f);
    p[t] = x * inv;
}

// ---------------------------------------------------------------------------
// offset [C=2048][D=1024] f32 -> offt [D][C] bf16 (LDS-tiled transpose),
// fused sum(offset^2) -> atomicAdd(reg_out). Tile: 64(c) x 64(d).
// ---------------------------------------------------------------------------
__global__ __launch_bounds__(256) void transpose_off(const float* __restrict__ off,
                                                     unsigned short* __restrict__ offt,
                                                     float* __restrict__ reg_out){
    __shared__ unsigned short t_lds[64][68];   // [d][c], padded row
    const int t  = threadIdx.x;
    const int c0 = blockIdx.x * 64;
    const int d0 = blockIdx.y * 64;
    float ss = 0.f;
    #pragma unroll
    for (int p = 0; p < 4; ++p){
        int c  = p * 16 + (t >> 4);
        int dq = t & 15;
        f32x4 v = *(const f32x4*)(off + (size_t)(c0 + c) * 1024 + d0 + dq * 4);
        ss += v[0]*v[0] + v[1]*v[1] + v[2]*v[2] + v[3]*v[3];
        #pragma unroll
        for (int j = 0; j < 4; ++j) t_lds[dq * 4 + j][c] = f2bf(v[j]);
    }
    __syncthreads();
    #pragma unroll
    for (int p = 0; p < 4; ++p){
        int d  = p * 16 + (t >> 4);
        int cq = t & 15;
        u16x4 o = *(const u16x4*)&t_lds[d][cq * 4];
        *(u16x4*)(offt + (size_t)(d0 + d) * 2048 + c0 + cq * 4) = o;
    }
    #pragma unroll
    for (int o = 32; o > 0; o >>= 1) ss += __shfl_xor(ss, o);
    __shared__ float red[4];
    if ((t & 63) == 0) red[t >> 6] = ss;
    __syncthreads();
    if (t == 0) atomicAdd(reg_out, red[0] + red[1] + red[2] + red[3]);
}

// ---------------------------------------------------------------------------
// GEMM: acc[m][n] = sum_k A[m][k] * B[n][k]   (both bf16, K-contiguous)
// 128x128 tile, BK=32, 256 threads (4 waves, 2x2), 16x16x32 bf16 MFMA,
// double-buffered LDS staged via global_load_lds width=16.
// EPI==1: Wout[m][n] = bf16(exp(10*acc - 10))        (ld = ldw)
// EPI==2: Fout[m][n] = Cadd[m][n] + acc              (ld = ldo)
// ---------------------------------------------------------------------------
template<int EPI>
__global__ __launch_bounds__(256, 2)
void gemm_bt(const unsigned short* __restrict__ A, int lda,
             const unsigned short* __restrict__ B, int ldb,
             int K,
             unsigned short* __restrict__ Wout, int ldw,
             const float* __restrict__ Cadd, float* __restrict__ Fout, int ldo)
{
    __shared__ unsigned short lds[2][2][4096];   // [buf][A/B][128*32] bf16 = 32 KiB
    const int tid  = threadIdx.x;
    const int m0   = blockIdx.x * 128;
    const int n0   = blockIdx.y * 128;
    const int wid  = tid >> 6, lane = tid & 63;
    const int wr   = wid >> 1, wc = wid & 1;
    const int kg   = lane >> 4, r16 = lane & 15;

    // staging: thread t covers row t/4 (and +64), 16B slot t%4 of a 64B row
    const int srow = tid >> 2;
    const int scol = (tid & 3) * 8;
    const unsigned short* gA0 = A + (size_t)(m0 + srow)      * lda + scol;
    const unsigned short* gA1 = A + (size_t)(m0 + 64 + srow) * lda + scol;
    const unsigned short* gB0 = B + (size_t)(n0 + srow)      * ldb + scol;
    const unsigned short* gB1 = B + (size_t)(n0 + 64 + srow) * ldb + scol;

    f32x4 acc[4][4] = {};

    const int nsteps = K >> 5;

    {   // prologue: stage k-step 0 into buf 0
        unsigned short* la = &lds[0][0][0];
        unsigned short* lb = &lds[0][1][0];
        gload16(gA0, la + tid * 8);
        gload16(gA1, la + 2048 + tid * 8);
        gload16(gB0, lb + tid * 8);
        gload16(gB1, lb + 2048 + tid * 8);
    }

    int cur = 0;
    for (int s = 0; s < nsteps; ++s){
        __syncthreads();                       // buf[cur] staged (vmcnt drained at barrier)
        if (s + 1 < nsteps){
            const int ko = (s + 1) << 5;
            unsigned short* la = &lds[cur ^ 1][0][0];
            unsigned short* lb = &lds[cur ^ 1][1][0];
            gload16(gA0 + ko, la + tid * 8);
            gload16(gA1 + ko, la + 2048 + tid * 8);
            gload16(gB0 + ko, lb + tid * 8);
            gload16(gB1 + ko, lb + 2048 + tid * 8);
        }
        const unsigned short* la = &lds[cur][0][0];
        const unsigned short* lb = &lds[cur][1][0];
        s16x8 af[4], bfr[4];
        #pragma unroll
        for (int m = 0; m < 4; ++m)
            af[m]  = *(const s16x8*)(la + (wr * 64 + m * 16 + r16) * 32 + kg * 8);
        #pragma unroll
        for (int n = 0; n < 4; ++n)
            bfr[n] = *(const s16x8*)(lb + (wc * 64 + n * 16 + r16) * 32 + kg * 8);
        #pragma unroll
        for (int m = 0; m < 4; ++m)
            #pragma unroll
            for (int n = 0; n < 4; ++n)
                mfma16(acc[m][n], af[m], bfr[n]);
        __syncthreads();                       // all waves done reading buf[cur]
        cur ^= 1;
    }

    asm volatile("s_nop 7\n\ts_nop 7");        // MFMA->VALU read hazard insurance

    const int crow = (lane >> 4) * 4;          // C/D: row = (lane>>4)*4 + reg
    const int ccol = lane & 15;                //      col = lane & 15

    #pragma unroll
    for (int m = 0; m < 4; ++m){
        #pragma unroll
        for (int n = 0; n < 4; ++n){
            const int gr = m0 + wr * 64 + m * 16 + crow;
            const int gc = n0 + wc * 64 + n * 16 + ccol;
            if (EPI == 1){
                #pragma unroll
                for (int r = 0; r < 4; ++r){
                    float sv = acc[m][n][r];
                    Wout[(size_t)(gr + r) * ldw + gc] = f2bf(__expf(10.0f * sv - 10.0f));
                }
            } else {
                #pragma unroll
                for (int r = 0; r < 4; ++r){
                    Fout[(size_t)(gr + r) * ldo + gc] =
                        Cadd[(size_t)(gr + r) * ldo + gc] + acc[m][n][r];
                }
            }
        }
    }
}

// ---------------------------------------------------------------------------
extern "C" void kernel_launch(void* const* d_in, const int* in_sizes, int n_in,
                              void* d_out, int out_size, void* d_ws, size_t ws_size,
                              hipStream_t stream)
{
    (void)n_in; (void)out_size;
    const float* inp = (const float*)d_in[0];
    const float* pos = (const float*)d_in[1];
    const float* off = (const float*)d_in[2];
    float* out = (float*)d_out;

    const int D = 1024, C = 2048;
    const int N = in_sizes[0] / D;            // 32768

    // workspace layout: b_bf[C*D] | offt[D*C] | a_bf[Mc*D] | w_buf[Mc*C]  (all bf16)
    unsigned short* b_bf = (unsigned short*)d_ws;
    unsigned short* offt = b_bf + (size_t)C * D;
    unsigned short* a_bf = offt + (size_t)D * C;
    size_t fixed = (size_t)C * D * 2 * 2;
    size_t avail = ws_size > fixed ? ws_size - fixed : 0;
    int Mc = 128;
    for (int cand = N; cand >= 128; cand >>= 1){
        if ((size_t)cand * (size_t)(D + C) * 2 <= avail){ Mc = cand; break; }
    }
    if (Mc > N) Mc = N;
    unsigned short* w_buf = a_bf + (size_t)Mc * D;

    float* reg_out = out + (size_t)N * D;
    hipMemsetAsync(reg_out, 0, sizeof(float), stream);

    transpose_off<<<dim3(C / 64, D / 64), 256, 0, stream>>>(off, offt, reg_out);
    norm_rows_bf16<<<C, 256, 0, stream>>>(pos, b_bf);

    for (int r0 = 0; r0 < N; r0 += Mc){
        norm_rows_bf16<<<Mc, 256, 0, stream>>>(inp + (size_t)r0 * D, a_bf);
        // GEMM1: W[Mc][C] = exp(10 * (a . b^T) - 10)
        gemm_bt<1><<<dim3(Mc / 128, C / 128), 256, 0, stream>>>(
            a_bf, D, b_bf, D, D, w_buf, C, nullptr, nullptr, 0);
        // GEMM2: out[Mc][D] = inp + W . offt^T
        gemm_bt<2><<<dim3(Mc / 128, D / 128), 256, 0, stream>>>(
            w_buf, C, offt, C, C, nullptr, 0, inp + (size_t)r0 * D, out + (size_t)r0 * D, D);
    }
    norm_rows_f32<<<N, 256, 0, stream>>>(out);
}

// Round 2
// 454.909 us; speedup vs baseline: 1.1020x; 1.1020x over previous
//
#include <hip/hip_runtime.h>

typedef float  f32x4 __attribute__((ext_vector_type(4)));
typedef short  s16x8 __attribute__((ext_vector_type(8)));
typedef unsigned short u16x4 __attribute__((ext_vector_type(4)));

#define AS1 __attribute__((address_space(1)))
#define AS3 __attribute__((address_space(3)))

__device__ __forceinline__ unsigned short f2bf(float x){
    union { float f; unsigned int u; } v; v.f = x;
    unsigned int r = v.u + 0x7FFFu + ((v.u >> 16) & 1u);   // RNE
    return (unsigned short)(r >> 16);
}

__device__ __forceinline__ void gload16(const unsigned short* g, const char* l){
    __builtin_amdgcn_global_load_lds((const AS1 void*)g, (AS3 void*)l, 16, 0, 0);
}

__device__ __forceinline__ void mfma16(f32x4& c, s16x8 a, s16x8 b){
    asm volatile("v_mfma_f32_16x16x32_bf16 %0, %1, %2, %0" : "+v"(c) : "v"(a), "v"(b));
}

// ---------------------------------------------------------------------------
// Row l2-normalize [rows][1024] f32 -> bf16. One 256-thread block per row.
// ---------------------------------------------------------------------------
__global__ __launch_bounds__(256) void norm_rows_bf16(const float* __restrict__ in,
                                                      unsigned short* __restrict__ out){
    const int row = blockIdx.x;
    const int t   = threadIdx.x;
    f32x4 x = ((const f32x4*)(in + (size_t)row * 1024))[t];
    float ss = x[0]*x[0] + x[1]*x[1] + x[2]*x[2] + x[3]*x[3];
    #pragma unroll
    for (int o = 32; o > 0; o >>= 1) ss += __shfl_xor(ss, o);
    __shared__ float red[4];
    if ((t & 63) == 0) red[t >> 6] = ss;
    __syncthreads();
    float tot = red[0] + red[1] + red[2] + red[3];
    float inv = 1.0f / fmaxf(sqrtf(tot), 1e-12f);
    u16x4 o;
    #pragma unroll
    for (int j = 0; j < 4; ++j) o[j] = f2bf(x[j] * inv);
    ((u16x4*)(out + (size_t)row * 1024))[t] = o;
}

// ---------------------------------------------------------------------------
// Final in-place row l2-normalize of d_out [N][1024] f32.
// ---------------------------------------------------------------------------
__global__ __launch_bounds__(256) void norm_rows_f32(float* __restrict__ buf){
    const int row = blockIdx.x;
    const int t   = threadIdx.x;
    f32x4* p = (f32x4*)(buf + (size_t)row * 1024);
    f32x4 x = p[t];
    float ss = x[0]*x[0] + x[1]*x[1] + x[2]*x[2] + x[3]*x[3];
    #pragma unroll
    for (int o = 32; o > 0; o >>= 1) ss += __shfl_xor(ss, o);
    __shared__ float red[4];
    if ((t & 63) == 0) red[t >> 6] = ss;
    __syncthreads();
    float tot = red[0] + red[1] + red[2] + red[3];
    float inv = 1.0f / fmaxf(sqrtf(tot), 1e-12f);
    p[t] = x * inv;
}

// ---------------------------------------------------------------------------
// offset [C=2048][D=1024] f32 -> offt [D][C] bf16 (LDS-tiled transpose),
// fused sum(offset^2) -> atomicAdd(reg_out). Tile: 64(c) x 64(d).
// ---------------------------------------------------------------------------
__global__ __launch_bounds__(256) void transpose_off(const float* __restrict__ off,
                                                     unsigned short* __restrict__ offt,
                                                     float* __restrict__ reg_out){
    __shared__ unsigned short t_lds[64][68];   // [d][c], padded row
    const int t  = threadIdx.x;
    const int c0 = blockIdx.x * 64;
    const int d0 = blockIdx.y * 64;
    float ss = 0.f;
    #pragma unroll
    for (int p = 0; p < 4; ++p){
        int c  = p * 16 + (t >> 4);
        int dq = t & 15;
        f32x4 v = *(const f32x4*)(off + (size_t)(c0 + c) * 1024 + d0 + dq * 4);
        ss += v[0]*v[0] + v[1]*v[1] + v[2]*v[2] + v[3]*v[3];
        #pragma unroll
        for (int j = 0; j < 4; ++j) t_lds[dq * 4 + j][c] = f2bf(v[j]);
    }
    __syncthreads();
    #pragma unroll
    for (int p = 0; p < 4; ++p){
        int d  = p * 16 + (t >> 4);
        int cq = t & 15;
        u16x4 o = *(const u16x4*)&t_lds[d][cq * 4];
        *(u16x4*)(offt + (size_t)(d0 + d) * 2048 + c0 + cq * 4) = o;
    }
    #pragma unroll
    for (int o = 32; o > 0; o >>= 1) ss += __shfl_xor(ss, o);
    __shared__ float red[4];
    if ((t & 63) == 0) red[t >> 6] = ss;
    __syncthreads();
    if (t == 0) atomicAdd(reg_out, red[0] + red[1] + red[2] + red[3]);
}

// ---------------------------------------------------------------------------
// GEMM: acc[m][n] = sum_k A[m][k] * B[n][k]   (both bf16, K-contiguous rows)
// 256x256 tile, BK=32, 512 threads (8 waves, 2Mx4N), quad-buffered 128 KiB
// LDS, counted-vmcnt pipeline (depth 3), XOR-swizzled LDS (T2 via
// pre-swizzled global source + swizzled ds_read).
// EPI==1: Wout[m][n] = bf16(exp(10*acc - 10))        (ld = ldw)
// EPI==2: Fout[m][n] = Cadd[m][n] + acc              (ld = ldo)
// ---------------------------------------------------------------------------
template<int EPI>
__global__ __launch_bounds__(512, 2)
void gemm256(const unsigned short* __restrict__ A, int lda,
             const unsigned short* __restrict__ B, int ldb,
             int K,
             unsigned short* __restrict__ Wout, int ldw,
             const float* __restrict__ Cadd, float* __restrict__ Fout, int ldo)
{
    extern __shared__ char smem[];             // 4 bufs x (A 16KB | B 16KB) = 128 KiB
    const int tid  = threadIdx.x;
    const int m0   = blockIdx.x * 256;
    const int n0   = blockIdx.y * 256;
    const int wid  = tid >> 6, lane = tid & 63;
    const int wr   = wid >> 2, wc = wid & 3;   // 2 x 4 waves, wave tile 128(M) x 64(N)
    const int kg   = lane >> 4, r16 = lane & 15;

    // ---- staging geometry: per matrix 16KB/tile = 2 granules(16B)/thread ----
    // phys byte p = ((wid*2+j)*64 + lane)*16 ; row = p>>6 ; logical kbyte =
    // (p&63) ^ (((p>>7)&3)<<4)  (involution; read side applies same XOR)
    const unsigned short* gA[2];
    const unsigned short* gB[2];
    int ldsA[2], ldsB[2];
    #pragma unroll
    for (int j = 0; j < 2; ++j){
        int p   = ((wid * 2 + j) * 64 + lane) * 16;
        int row = p >> 6;
        int kb  = (p & 63) ^ (((p >> 7) & 3) << 4);
        gA[j]   = A + (size_t)(m0 + row) * lda + (kb >> 1);
        gB[j]   = B + (size_t)(n0 + row) * ldb + (kb >> 1);
        ldsA[j] = p;
        ldsB[j] = 16384 + p;
    }

    // ---- ds_read fragment offsets (swizzled) ----
    int aoff[8], boff[4];
    #pragma unroll
    for (int m = 0; m < 8; ++m){
        int row = wr * 128 + m * 16 + r16;
        int o   = row * 64 + kg * 16;
        aoff[m] = o ^ ((((o >> 7) & 3) << 4));
    }
    #pragma unroll
    for (int n = 0; n < 4; ++n){
        int row = wc * 64 + n * 16 + r16;
        int o   = row * 64 + kg * 16;
        boff[n] = 16384 + (o ^ ((((o >> 7) & 3) << 4)));
    }

    f32x4 acc[8][4] = {};
    const int nsteps = K >> 5;

    // ---- prologue: stage tiles 0,1,2 ----
    #pragma unroll
    for (int i = 0; i < 3; ++i){
        if (i < nsteps){
            char* base = smem + (i << 15);
            #pragma unroll
            for (int j = 0; j < 2; ++j){
                gload16(gA[j] + i * 32, base + ldsA[j]);
                gload16(gB[j] + i * 32, base + ldsB[j]);
            }
        }
    }

    #pragma unroll 1
    for (int t = 0; t < nsteps; ++t){
        // wait until this tile's 4 loads (per thread) have landed; keep up to
        // 8 (tiles t+1,t+2) in flight.  vmcnt is FIFO: 4 loads/tile.
        const int rem = nsteps - 1 - t;
        if (rem >= 2)      asm volatile("s_waitcnt vmcnt(8)" ::: "memory");
        else if (rem == 1) asm volatile("s_waitcnt vmcnt(4)" ::: "memory");
        else               asm volatile("s_waitcnt vmcnt(0)" ::: "memory");
        __builtin_amdgcn_s_barrier();          // all waves: tile t visible; tile t-1 reads done
        asm volatile("" ::: "memory");
        __builtin_amdgcn_sched_barrier(0);

        // issue prefetch for tile t+3 into buf[(t+3)&3] (last read at t-1)
        if (t + 3 < nsteps){
            char* base = smem + (((t + 3) & 3) << 15);
            const int ko = (t + 3) * 32;
            #pragma unroll
            for (int j = 0; j < 2; ++j){
                gload16(gA[j] + ko, base + ldsA[j]);
                gload16(gB[j] + ko, base + ldsB[j]);
            }
        }

        const char* base = smem + ((t & 3) << 15);
        s16x8 a[8], b[4];
        #pragma unroll
        for (int m = 0; m < 8; ++m) a[m] = *(const s16x8*)(base + aoff[m]);
        #pragma unroll
        for (int n = 0; n < 4; ++n) b[n] = *(const s16x8*)(base + boff[n]);

        __builtin_amdgcn_s_setprio(1);
        #pragma unroll
        for (int m = 0; m < 8; ++m)
            #pragma unroll
            for (int n = 0; n < 4; ++n)
                mfma16(acc[m][n], a[m], b[n]);
        __builtin_amdgcn_s_setprio(0);
    }

    asm volatile("s_nop 7\n\ts_nop 7");        // MFMA->VALU read hazard insurance

    const int crow = (lane >> 4) * 4;          // C/D: row = (lane>>4)*4 + reg
    const int ccol = lane & 15;                //      col = lane & 15

    #pragma unroll
    for (int m = 0; m < 8; ++m){
        #pragma unroll
        for (int n = 0; n < 4; ++n){
            const int gr = m0 + wr * 128 + m * 16 + crow;
            const int gc = n0 + wc * 64  + n * 16 + ccol;
            if (EPI == 1){
                #pragma unroll
                for (int r = 0; r < 4; ++r){
                    float sv = acc[m][n][r];
                    Wout[(size_t)(gr + r) * ldw + gc] = f2bf(__expf(10.0f * sv - 10.0f));
                }
            } else {
                #pragma unroll
                for (int r = 0; r < 4; ++r){
                    Fout[(size_t)(gr + r) * ldo + gc] =
                        Cadd[(size_t)(gr + r) * ldo + gc] + acc[m][n][r];
                }
            }
        }
    }
}

// ---------------------------------------------------------------------------
extern "C" void kernel_launch(void* const* d_in, const int* in_sizes, int n_in,
                              void* d_out, int out_size, void* d_ws, size_t ws_size,
                              hipStream_t stream)
{
    (void)n_in; (void)out_size;
    const float* inp = (const float*)d_in[0];
    const float* pos = (const float*)d_in[1];
    const float* off = (const float*)d_in[2];
    float* out = (float*)d_out;

    const int D = 1024, C = 2048;
    const int N = in_sizes[0] / D;            // 32768

    // workspace layout: b_bf[C*D] | offt[D*C] | a_bf[Mc*D] | w_buf[Mc*C]  (all bf16)
    unsigned short* b_bf = (unsigned short*)d_ws;
    unsigned short* offt = b_bf + (size_t)C * D;
    unsigned short* a_bf = offt + (size_t)D * C;
    size_t fixed = (size_t)C * D * 2 * 2;
    size_t avail = ws_size > fixed ? ws_size - fixed : 0;
    int Mc = 256;
    for (int cand = N; cand >= 256; cand >>= 1){
        if ((size_t)cand * (size_t)(D + C) * 2 <= avail){ Mc = cand; break; }
    }
    if (Mc > N) Mc = N;
    unsigned short* w_buf = a_bf + (size_t)Mc * D;

    hipFuncSetAttribute(reinterpret_cast<const void*>(&gemm256<1>),
                        hipFuncAttributeMaxDynamicSharedMemorySize, 131072);
    hipFuncSetAttribute(reinterpret_cast<const void*>(&gemm256<2>),
                        hipFuncAttributeMaxDynamicSharedMemorySize, 131072);

    float* reg_out = out + (size_t)N * D;
    hipMemsetAsync(reg_out, 0, sizeof(float), stream);

    transpose_off<<<dim3(C / 64, D / 64), 256, 0, stream>>>(off, offt, reg_out);
    norm_rows_bf16<<<C, 256, 0, stream>>>(pos, b_bf);

    for (int r0 = 0; r0 < N; r0 += Mc){
        norm_rows_bf16<<<Mc, 256, 0, stream>>>(inp + (size_t)r0 * D, a_bf);
        // GEMM1: W[Mc][C] = exp(10 * (a . b^T) - 10)
        gemm256<1><<<dim3(Mc / 256, C / 256), 512, 131072, stream>>>(
            a_bf, D, b_bf, D, D, w_buf, C, nullptr, nullptr, 0);
        // GEMM2: out[Mc][D] = inp + W . offt^T
        gemm256<2><<<dim3(Mc / 256, D / 256), 512, 131072, stream>>>(
            w_buf, C, offt, C, C, nullptr, 0, inp + (size_t)r0 * D, out + (size_t)r0 * D, D);
    }
    norm_rows_f32<<<N, 256, 0, stream>>>(out);
}

// Round 3
// 425.004 us; speedup vs baseline: 1.1795x; 1.0704x over previous
//
#include <hip/hip_runtime.h>

typedef float  f32x4 __attribute__((ext_vector_type(4)));
typedef short  s16x8 __attribute__((ext_vector_type(8)));
typedef unsigned short u16x4 __attribute__((ext_vector_type(4)));

#define AS1 __attribute__((address_space(1)))
#define AS3 __attribute__((address_space(3)))

__device__ __forceinline__ unsigned short f2bf(float x){
    union { float f; unsigned int u; } v; v.f = x;
    unsigned int r = v.u + 0x7FFFu + ((v.u >> 16) & 1u);   // RNE
    return (unsigned short)(r >> 16);
}

__device__ __forceinline__ void gload16(const unsigned short* g, const char* l){
    __builtin_amdgcn_global_load_lds((const AS1 void*)g, (AS3 void*)l, 16, 0, 0);
}

__device__ __forceinline__ void mfma16(f32x4& c, s16x8 a, s16x8 b){
    asm volatile("v_mfma_f32_16x16x32_bf16 %0, %1, %2, %0" : "+v"(c) : "v"(a), "v"(b));
}

#define PH_MIDBAR() do{ asm volatile("" ::: "memory"); __builtin_amdgcn_s_barrier(); \
    asm volatile("s_waitcnt lgkmcnt(0)" ::: "memory"); __builtin_amdgcn_sched_barrier(0); }while(0)
#define PH_ENDBAR() do{ asm volatile("" ::: "memory"); __builtin_amdgcn_s_barrier(); }while(0)

// ---------------------------------------------------------------------------
// Row l2-normalize [rows][1024] f32 -> bf16. One 256-thread block per row.
// ---------------------------------------------------------------------------
__global__ __launch_bounds__(256) void norm_rows_bf16(const float* __restrict__ in,
                                                      unsigned short* __restrict__ out){
    const int row = blockIdx.x;
    const int t   = threadIdx.x;
    f32x4 x = ((const f32x4*)(in + (size_t)row * 1024))[t];
    float ss = x[0]*x[0] + x[1]*x[1] + x[2]*x[2] + x[3]*x[3];
    #pragma unroll
    for (int o = 32; o > 0; o >>= 1) ss += __shfl_xor(ss, o);
    __shared__ float red[4];
    if ((t & 63) == 0) red[t >> 6] = ss;
    __syncthreads();
    float tot = red[0] + red[1] + red[2] + red[3];
    float inv = 1.0f / fmaxf(sqrtf(tot), 1e-12f);
    u16x4 o;
    #pragma unroll
    for (int j = 0; j < 4; ++j) o[j] = f2bf(x[j] * inv);
    ((u16x4*)(out + (size_t)row * 1024))[t] = o;
}

// ---------------------------------------------------------------------------
// Final in-place row l2-normalize of d_out [N][1024] f32.
// ---------------------------------------------------------------------------
__global__ __launch_bounds__(256) void norm_rows_f32(float* __restrict__ buf){
    const int row = blockIdx.x;
    const int t   = threadIdx.x;
    f32x4* p = (f32x4*)(buf + (size_t)row * 1024);
    f32x4 x = p[t];
    float ss = x[0]*x[0] + x[1]*x[1] + x[2]*x[2] + x[3]*x[3];
    #pragma unroll
    for (int o = 32; o > 0; o >>= 1) ss += __shfl_xor(ss, o);
    __shared__ float red[4];
    if ((t & 63) == 0) red[t >> 6] = ss;
    __syncthreads();
    float tot = red[0] + red[1] + red[2] + red[3];
    float inv = 1.0f / fmaxf(sqrtf(tot), 1e-12f);
    p[t] = x * inv;
}

// ---------------------------------------------------------------------------
// offset [C=2048][D=1024] f32 -> offt [D][C] bf16 (LDS-tiled transpose),
// fused sum(offset^2) -> atomicAdd(reg_out). Tile: 64(c) x 64(d).
// ---------------------------------------------------------------------------
__global__ __launch_bounds__(256) void transpose_off(const float* __restrict__ off,
                                                     unsigned short* __restrict__ offt,
                                                     float* __restrict__ reg_out){
    __shared__ unsigned short t_lds[64][68];   // [d][c], padded row
    const int t  = threadIdx.x;
    const int c0 = blockIdx.x * 64;
    const int d0 = blockIdx.y * 64;
    float ss = 0.f;
    #pragma unroll
    for (int p = 0; p < 4; ++p){
        int c  = p * 16 + (t >> 4);
        int dq = t & 15;
        f32x4 v = *(const f32x4*)(off + (size_t)(c0 + c) * 1024 + d0 + dq * 4);
        ss += v[0]*v[0] + v[1]*v[1] + v[2]*v[2] + v[3]*v[3];
        #pragma unroll
        for (int j = 0; j < 4; ++j) t_lds[dq * 4 + j][c] = f2bf(v[j]);
    }
    __syncthreads();
    #pragma unroll
    for (int p = 0; p < 4; ++p){
        int d  = p * 16 + (t >> 4);
        int cq = t & 15;
        u16x4 o = *(const u16x4*)&t_lds[d][cq * 4];
        *(u16x4*)(offt + (size_t)(d0 + d) * 2048 + c0 + cq * 4) = o;
    }
    #pragma unroll
    for (int o = 32; o > 0; o >>= 1) ss += __shfl_xor(ss, o);
    __shared__ float red[4];
    if ((t & 63) == 0) red[t >> 6] = ss;
    __syncthreads();
    if (t == 0) atomicAdd(reg_out, red[0] + red[1] + red[2] + red[3]);
}

// ---------------------------------------------------------------------------
// GEMM: acc[m][n] = sum_k A[m][k] * B[n][k]   (both bf16, K-contiguous rows)
// 256x256 tile, BK=64, 512 threads (8 waves, 2Mx4N; wave tile 128x64).
// Double-buffered 128 KiB LDS; each buffer = [Ak0|Bk0|Ak1|Bk1] 16KB K-half
// blocks (rows x 32 k-elems, 64B rows, XOR granule swizzle g^=((row>>1)&3)
// applied via pre-swizzled global source + swizzled ds_read).
// 4 phases / K-tile (8-phase template, m201): per phase
//   {ds_read frags | issue 1 half-tile gload_lds} -> barrier -> lgkmcnt(0)
//   -> setprio(1) + 16 MFMA + setprio(0) -> [vmcnt(4)] -> barrier
// Counted vmcnt(4) twice per K-tile; never 0 in steady state.
// EPI==1: Wout[m][n] = bf16(exp(10*acc - 10))        (ld = ldw)
// EPI==2: Fout[m][n] = Cadd[m][n] + acc              (ld = ldo)
// ---------------------------------------------------------------------------
template<int EPI>
__global__ __launch_bounds__(512, 2)
void gemm256(const unsigned short* __restrict__ A, int lda,
             const unsigned short* __restrict__ B, int ldb,
             int K,
             unsigned short* __restrict__ Wout, int ldw,
             const float* __restrict__ Cadd, float* __restrict__ Fout, int ldo)
{
    extern __shared__ char smem[];             // 2 x 64 KiB
    const int tid  = threadIdx.x;
    const int m0   = blockIdx.x * 256;
    const int n0   = blockIdx.y * 256;
    const int wid  = tid >> 6, lane = tid & 63;
    const int wr   = wid >> 2, wc = wid & 3;   // 2 x 4 waves
    const int kg   = lane >> 4, r16 = lane & 15;

    // ---- staging: per 16KB half-block, thread covers phys bytes tid*16 and
    // 8192+tid*16. phys granule g=(tid&3) at row tid>>2 (and +128) holds
    // logical granule g^((row>>1)&3) -> pre-swizzled global source.
    const int srow = tid >> 2;
    const int sg   = (tid & 3) ^ ((tid >> 3) & 3);
    const unsigned short* sA0 = A + (size_t)(m0 + srow)       * lda + sg * 8;
    const unsigned short* sA1 = A + (size_t)(m0 + 128 + srow) * lda + sg * 8;
    const unsigned short* sB0 = B + (size_t)(n0 + srow)       * ldb + sg * 8;
    const unsigned short* sB1 = B + (size_t)(n0 + 128 + srow) * ldb + sg * 8;
    const int lp0 = tid * 16, lp1 = 8192 + tid * 16;

    auto stageA = [&](char* wb, int blk, int ke){
        gload16(sA0 + ke, wb + blk * 16384 + lp0);
        gload16(sA1 + ke, wb + blk * 16384 + lp1);
    };
    auto stageB = [&](char* wb, int blk, int ke){
        gload16(sB0 + ke, wb + blk * 16384 + lp0);
        gload16(sB1 + ke, wb + blk * 16384 + lp1);
    };

    // ---- ds_read fragment offsets (within a K-half block; swizzled) ----
    int aoff[8], boff[4];
    #pragma unroll
    for (int m = 0; m < 8; ++m){
        int row = wr * 128 + m * 16 + r16;
        aoff[m] = row * 64 + ((kg ^ ((row >> 1) & 3)) << 4);
    }
    #pragma unroll
    for (int n = 0; n < 4; ++n){
        int row = wc * 64 + n * 16 + r16;
        boff[n] = 16384 + row * 64 + ((kg ^ ((row >> 1) & 3)) << 4);
    }

    f32x4 acc[8][4] = {};
    s16x8 alo[4], ahi[4], bf[4];
    const int nsteps = K >> 6;                 // BK = 64

    // ---- prologue: stage tile 0 (Ak0,Bk0,Ak1,Bk1) ----
    {
        char* wb = smem;
        stageA(wb, 0, 0);  stageB(wb, 1, 0);
        stageA(wb, 2, 32); stageB(wb, 3, 32);
    }
    asm volatile("s_waitcnt vmcnt(4)" ::: "memory");   // Ak0,Bk0 landed
    __builtin_amdgcn_s_barrier();

#define LD_ALO(rb, ks) { _Pragma("unroll") for (int m = 0; m < 4; ++m) \
    alo[m] = *(const s16x8*)((rb) + (ks) * 32768 + aoff[m]); }
#define LD_AHI(rb, ks) { _Pragma("unroll") for (int m = 0; m < 4; ++m) \
    ahi[m] = *(const s16x8*)((rb) + (ks) * 32768 + aoff[m + 4]); }
#define LD_B(rb, ks)   { _Pragma("unroll") for (int n = 0; n < 4; ++n) \
    bf[n]  = *(const s16x8*)((rb) + (ks) * 32768 + boff[n]); }
#define MFMA_LO() { __builtin_amdgcn_s_setprio(1); \
    _Pragma("unroll") for (int m = 0; m < 4; ++m) \
    _Pragma("unroll") for (int n = 0; n < 4; ++n) \
        mfma16(acc[m][n], alo[m], bf[n]); \
    __builtin_amdgcn_s_setprio(0); }
#define MFMA_HI() { __builtin_amdgcn_s_setprio(1); \
    _Pragma("unroll") for (int m = 0; m < 4; ++m) \
    _Pragma("unroll") for (int n = 0; n < 4; ++n) \
        mfma16(acc[m + 4][n], ahi[m], bf[n]); \
    __builtin_amdgcn_s_setprio(0); }

    #pragma unroll 1
    for (int t = 0; t < nsteps - 1; ++t){
        const char* rb = smem + (t & 1) * 65536;
        char*       wb = smem + ((t + 1) & 1) * 65536;
        const int   ke = (t + 1) * 64;
        // P0: read (ks0: A m0-3, B), stage Ak0(t+1)
        LD_ALO(rb, 0); LD_B(rb, 0);
        stageA(wb, 0, ke);
        PH_MIDBAR();
        MFMA_LO();
        PH_ENDBAR();
        // P1: read (ks0: A m4-7), stage Bk0(t+1)
        LD_AHI(rb, 0);
        stageB(wb, 1, ke);
        PH_MIDBAR();
        MFMA_HI();
        asm volatile("s_waitcnt vmcnt(4)" ::: "memory");  // Ak1(t),Bk1(t) landed
        PH_ENDBAR();
        // P2: read (ks1: A m0-3, B), stage Ak1(t+1)
        LD_ALO(rb, 1); LD_B(rb, 1);
        stageA(wb, 2, ke + 32);
        PH_MIDBAR();
        MFMA_LO();
        PH_ENDBAR();
        // P3: read (ks1: A m4-7), stage Bk1(t+1)
        LD_AHI(rb, 1);
        stageB(wb, 3, ke + 32);
        PH_MIDBAR();
        MFMA_HI();
        asm volatile("s_waitcnt vmcnt(4)" ::: "memory");  // Ak0,Bk0(t+1) landed
        PH_ENDBAR();
    }
    {   // ---- last K-tile (no staging; drain at P1) ----
        const char* rb = smem + ((nsteps - 1) & 1) * 65536;
        LD_ALO(rb, 0); LD_B(rb, 0);
        PH_MIDBAR();
        MFMA_LO();
        PH_ENDBAR();
        LD_AHI(rb, 0);
        PH_MIDBAR();
        MFMA_HI();
        asm volatile("s_waitcnt vmcnt(0)" ::: "memory");  // Ak1,Bk1(last) landed
        PH_ENDBAR();
        LD_ALO(rb, 1); LD_B(rb, 1);
        PH_MIDBAR();
        MFMA_LO();
        PH_ENDBAR();
        LD_AHI(rb, 1);
        PH_MIDBAR();
        MFMA_HI();
    }

    asm volatile("s_nop 7\n\ts_nop 7");        // MFMA->VALU read hazard insurance

    const int crow = (lane >> 4) * 4;          // C/D: row = (lane>>4)*4 + reg
    const int ccol = lane & 15;                //      col = lane & 15

    #pragma unroll
    for (int m = 0; m < 8; ++m){
        #pragma unroll
        for (int n = 0; n < 4; ++n){
            const int gr = m0 + wr * 128 + m * 16 + crow;
            const int gc = n0 + wc * 64  + n * 16 + ccol;
            if (EPI == 1){
                #pragma unroll
                for (int r = 0; r < 4; ++r){
                    float sv = acc[m][n][r];
                    Wout[(size_t)(gr + r) * ldw + gc] = f2bf(__expf(10.0f * sv - 10.0f));
                }
            } else {
                #pragma unroll
                for (int r = 0; r < 4; ++r){
                    Fout[(size_t)(gr + r) * ldo + gc] =
                        Cadd[(size_t)(gr + r) * ldo + gc] + acc[m][n][r];
                }
            }
        }
    }
#undef LD_ALO
#undef LD_AHI
#undef LD_B
#undef MFMA_LO
#undef MFMA_HI
}

// ---------------------------------------------------------------------------
extern "C" void kernel_launch(void* const* d_in, const int* in_sizes, int n_in,
                              void* d_out, int out_size, void* d_ws, size_t ws_size,
                              hipStream_t stream)
{
    (void)n_in; (void)out_size;
    const float* inp = (const float*)d_in[0];
    const float* pos = (const float*)d_in[1];
    const float* off = (const float*)d_in[2];
    float* out = (float*)d_out;

    const int D = 1024, C = 2048;
    const int N = in_sizes[0] / D;            // 32768

    // workspace layout: b_bf[C*D] | offt[D*C] | a_bf[Mc*D] | w_buf[Mc*C]  (all bf16)
    unsigned short* b_bf = (unsigned short*)d_ws;
    unsigned short* offt = b_bf + (size_t)C * D;
    unsigned short* a_bf = offt + (size_t)D * C;
    size_t fixed = (size_t)C * D * 2 * 2;
    size_t avail = ws_size > fixed ? ws_size - fixed : 0;
    int Mc = 256;
    for (int cand = N; cand >= 256; cand >>= 1){
        if ((size_t)cand * (size_t)(D + C) * 2 <= avail){ Mc = cand; break; }
    }
    if (Mc > N) Mc = N;
    unsigned short* w_buf = a_bf + (size_t)Mc * D;

    hipFuncSetAttribute(reinterpret_cast<const void*>(&gemm256<1>),
                        hipFuncAttributeMaxDynamicSharedMemorySize, 131072);
    hipFuncSetAttribute(reinterpret_cast<const void*>(&gemm256<2>),
                        hipFuncAttributeMaxDynamicSharedMemorySize, 131072);

    float* reg_out = out + (size_t)N * D;
    hipMemsetAsync(reg_out, 0, sizeof(float), stream);

    transpose_off<<<dim3(C / 64, D / 64), 256, 0, stream>>>(off, offt, reg_out);
    norm_rows_bf16<<<C, 256, 0, stream>>>(pos, b_bf);

    for (int r0 = 0; r0 < N; r0 += Mc){
        norm_rows_bf16<<<Mc, 256, 0, stream>>>(inp + (size_t)r0 * D, a_bf);
        // GEMM1: W[Mc][C] = exp(10 * (a . b^T) - 10)
        gemm256<1><<<dim3(Mc / 256, C / 256), 512, 131072, stream>>>(
            a_bf, D, b_bf, D, D, w_buf, C, nullptr, nullptr, 0);
        // GEMM2: out[Mc][D] = inp + W . offt^T
        gemm256<2><<<dim3(Mc / 256, D / 256), 512, 131072, stream>>>(
            w_buf, C, offt, C, C, nullptr, 0, inp + (size_t)r0 * D, out + (size_t)r0 * D, D);
    }
    norm_rows_f32<<<N, 256, 0, stream>>>(out);
}